// Round 11
// baseline (115.823 us; speedup 1.0000x reference)
//
#include <hip/hip_runtime.h>

#define M_NODES 8192
#define K_PAR 8
#define C_CFG 256
#define N_LAYERS 8
#define TPB 1024
#define NBLOCKS 256      // 16 waves/block * 256 = 4096 waves: all co-resident
#define WPB (TPB / 64)   // 16 waves/block
#define NPB (WPB * 2)    // 32 nodes/block/layer
#define NSHARD 32        // counter shards per layer (8 blocks each)
#define SHARD_STRIDE 1024 // 4 KB apart -> different L3/MALL slices (parallel RMW)
#define GATE_TARGET 256u // 8 blocks/shard * 32 nodes/block
#define NLINES ((N_LAYERS + 1) * NSHARD)

__device__ __forceinline__ float fsig(float x) {
    return __builtin_amdgcn_rcpf(1.0f + __expf(-x));
}
__device__ __forceinline__ float aloadf(const float* p) {
    return __hip_atomic_load(p, __ATOMIC_RELAXED, __HIP_MEMORY_SCOPE_AGENT);
}
__device__ __forceinline__ unsigned aloadu(const unsigned* p) {
    return __hip_atomic_load(p, __ATOMIC_RELAXED, __HIP_MEMORY_SCOPE_AGENT);
}
__device__ __forceinline__ void astoref(float* p, float v) {
    __hip_atomic_store(p, v, __ATOMIC_RELAXED, __HIP_MEMORY_SCOPE_AGENT);
}
__device__ __forceinline__ void astore2(float* p, float lo, float hi) {
    union { float f[2]; unsigned long long u; } v;
    v.f[0] = lo; v.f[1] = hi;
    __hip_atomic_store((unsigned long long*)p, v.u, __ATOMIC_RELAXED, __HIP_MEMORY_SCOPE_AGENT);
}

// Zero only the polled word of each shard line (288 words). Stream-ordered
// before the main kernel; replay-proof (no dependence on ws poison value).
__global__ __launch_bounds__(512) void init_rdy(unsigned* rdy) {
    int i = threadIdx.x;
    if (i < NLINES) rdy[(size_t)i * SHARD_STRIDE] = 0u;
}

// cpt/parents NOT __restrict__: publishes to `out` may alias, so the compiler
// cannot sink the depth-1 CPT prefetch past the publish stores (R6-verified).
__global__ __launch_bounds__(TPB, 4) void bayes_flow6(
    const float* root_logits,   // [M]
    const float* cpt,           // [L, M, C]
    const int*   parents,       // [L, M, K]
    float*       out,           // [(L+1)*M]
    unsigned*    rdy)           // [(L+1)*NSHARD*SHARD_STRIDE], word 0/line zeroed
{
    const int tid   = threadIdx.x;
    const int lane  = tid & 63;
    const int b     = blockIdx.x;
    const int gwave = b * WPB + (tid >> 6);
    const int mA    = gwave << 1;   // block owns contiguous nodes [b*32, b*32+32)
    const int mB    = mA | 1;
    const int c0    = lane << 2;
    const int shard = b >> 3;       // 8 blocks per shard, 32 shards

    // ---- issue root + parent-index + layer-0 CPT loads up front ----
    float rl = 0.0f;
    if (tid < NPB) rl = root_logits[b * NPB + tid];

    int pidx[N_LAYERS];
    if (lane < 2 * K_PAR) {
        const int node = (lane < K_PAR) ? mA : mB;
#pragma unroll
        for (int l = 0; l < N_LAYERS; ++l)
            pidx[l] = parents[((size_t)l * M_NODES + node) * K_PAR + (lane & 7)];
    }

    float4 qAc = *reinterpret_cast<const float4*>(cpt + (size_t)mA * C_CFG + c0);
    float4 qBc = *reinterpret_cast<const float4*>(cpt + (size_t)mB * C_CFG + c0);

    // publish roots (value>0 == ready), then count them for layer-0's gate.
    // __syncthreads drains every wave's vmcnt first (compiler-enforced), so the
    // add follows all of this block's value stores in the memory pipe.
    if (tid < NPB) astoref(out + b * NPB + tid, fsig(rl));
    __syncthreads();
    if (tid == 0)
        __hip_atomic_fetch_add(rdy + (size_t)shard * SHARD_STRIDE, 32u,
                               __ATOMIC_RELAXED, __HIP_MEMORY_SCOPE_AGENT);

    const float* prev = out;
    float*       cur  = out + M_NODES;

#pragma unroll
    for (int l = 0; l < N_LAYERS; ++l) {
        // (1) issue NEXT layer's CPT loads — stream from HBM during the gate wait
        float4 qAn = {0, 0, 0, 0}, qBn = {0, 0, 0, 0};
        if (l + 1 < N_LAYERS) {
            qAn = *reinterpret_cast<const float4*>(cpt + ((size_t)(l + 1) * M_NODES + mA) * C_CFG + c0);
            qBn = *reinterpret_cast<const float4*>(cpt + ((size_t)(l + 1) * M_NODES + mB) * C_CFG + c0);
        }

        // (2) parent-independent VALU work before the wait
        const float sA0 = fsig(qAc.x), sA1 = fsig(qAc.y), sA2 = fsig(qAc.z), sA3 = fsig(qAc.w);
        const float sB0 = fsig(qBc.x), sB1 = fsig(qBc.y), sB2 = fsig(qBc.z), sB3 = fsig(qBc.w);

        // (3) gate: wave 0 polls layer l's 32 shard counters (one load instr,
        // 32 lanes x 32 slice-spread lines). Budgeted; (4) guards correctness.
        if (tid < 64) {
            const unsigned* base = rdy + (size_t)l * NSHARD * SHARD_STRIDE;
            int budget = 1 << 22;
            for (;;) {
                bool ok = true;
                if (lane < NSHARD) ok = (aloadu(base + (size_t)lane * SHARD_STRIDE) >= GATE_TARGET);
                if (__all(ok) || --budget <= 0) break;
                __builtin_amdgcn_s_sleep(1);
            }
        }
        __syncthreads();

        // (4) gather parent marginals; value>0 re-check is the true correctness
        // guard. First retries spin hot (no sleep) — straggler window is short.
        float pv = 1.0f;
        if (lane < 2 * K_PAR) {
            const float* ap = prev + pidx[l];
            pv = aloadf(ap);
            int tries = 0;
            while (!(pv > 0.0f)) {
                if (++tries > 4) __builtin_amdgcn_s_sleep(2);
                pv = aloadf(ap);
            }
        }

        // (5) broadcast the 8 parent marginals of each node to all 64 lanes
        float pAv[K_PAR], pBv[K_PAR];
#pragma unroll
        for (int j = 0; j < K_PAR; ++j) {
            pAv[j] = __shfl(pv, j, 64);
            pBv[j] = __shfl(pv, K_PAR + j, 64);
        }

        // (6) config weights: top 6 bits fixed per lane, last 2 = lane's 4 configs
        float prefA = 1.0f, prefB = 1.0f;
#pragma unroll
        for (int j = 0; j < 6; ++j) {
            const int bit = (c0 >> (7 - j)) & 1;
            prefA *= bit ? pAv[j] : (1.0f - pAv[j]);
            prefB *= bit ? pBv[j] : (1.0f - pBv[j]);
        }
        const float p6A = pAv[6], p7A = pAv[7], q6A = 1.0f - p6A, q7A = 1.0f - p7A;
        const float p6B = pBv[6], p7B = pBv[7], q6B = 1.0f - p6B, q7B = 1.0f - p7B;

        float sA = sA0 * (prefA * q6A * q7A) + sA1 * (prefA * q6A * p7A)
                 + sA2 * (prefA * p6A * q7A) + sA3 * (prefA * p6A * p7A);
        float sB = sB0 * (prefB * q6B * q7B) + sB1 * (prefB * q6B * p7B)
                 + sB2 * (prefB * p6B * q7B) + sB3 * (prefB * p6B * p7B);

        // (7) 64-lane reductions; lane0 publishes both nodes in one 8B store
#pragma unroll
        for (int off = 32; off; off >>= 1) {
            sA += __shfl_xor(sA, off, 64);
            sB += __shfl_xor(sB, off, 64);
        }
        if (lane == 0) astore2(cur + mA, sA, sB);

        // (8) count this block's publishes for layer l+1's gate
        if (l + 1 < N_LAYERS) {
            __syncthreads();
            if (tid == 0)
                __hip_atomic_fetch_add(rdy + ((size_t)(l + 1) * NSHARD + shard) * SHARD_STRIDE,
                                       32u, __ATOMIC_RELAXED, __HIP_MEMORY_SCOPE_AGENT);
        }

        // (9) rotate + pin prefetched CPT regs (holds them in VGPRs; R6-verified)
        qAc = qAn; qBc = qBn;
        asm volatile("" : "+v"(qAc.x), "+v"(qAc.y), "+v"(qAc.z), "+v"(qAc.w),
                          "+v"(qBc.x), "+v"(qBc.y), "+v"(qBc.z), "+v"(qBc.w));

        prev = cur;
        cur += M_NODES;
    }
}

extern "C" void kernel_launch(void* const* d_in, const int* in_sizes, int n_in,
                              void* d_out, int out_size, void* d_ws, size_t ws_size,
                              hipStream_t stream) {
    const float* root_logits = (const float*)d_in[0];
    const float* cpt_logits  = (const float*)d_in[1];
    const int*   parents     = (const int*)d_in[2];
    float*       out         = (float*)d_out;
    unsigned*    rdy         = (unsigned*)d_ws;

    init_rdy<<<1, 512, 0, stream>>>(rdy);
    bayes_flow6<<<NBLOCKS, TPB, 0, stream>>>(root_logits, cpt_logits, parents, out, rdy);
}

// Round 12
// 112.203 us; speedup vs baseline: 1.0323x; 1.0323x over previous
//
#include <hip/hip_runtime.h>

#define M_NODES 8192
#define K_PAR 8
#define C_CFG 256
#define N_LAYERS 8
#define TPB 1024
#define NBLOCKS 256      // 16 waves/block * 256 = 4096 waves: all co-resident
#define WPB (TPB / 64)   // 16 waves/block
#define NPB (WPB * 2)    // 32 nodes/block/layer
#define NSHARD 32        // counter shards per layer (8 blocks each)
#define SHARD_STRIDE 1024 // 4 KB apart -> different L3/MALL slices (parallel RMW)
#define GATE_TARGET 256u // 8 blocks/shard * 32 nodes/block
#define NLINES ((N_LAYERS + 1) * NSHARD)

__device__ __forceinline__ float fsig(float x) {
    return __builtin_amdgcn_rcpf(1.0f + __expf(-x));
}
__device__ __forceinline__ float aloadf(const float* p) {
    return __hip_atomic_load(p, __ATOMIC_RELAXED, __HIP_MEMORY_SCOPE_AGENT);
}
__device__ __forceinline__ unsigned aloadu(const unsigned* p) {
    return __hip_atomic_load(p, __ATOMIC_RELAXED, __HIP_MEMORY_SCOPE_AGENT);
}
__device__ __forceinline__ void astoref(float* p, float v) {
    __hip_atomic_store(p, v, __ATOMIC_RELAXED, __HIP_MEMORY_SCOPE_AGENT);
}
__device__ __forceinline__ void astore2(float* p, float lo, float hi) {
    union { float f[2]; unsigned long long u; } v;
    v.f[0] = lo; v.f[1] = hi;
    __hip_atomic_store((unsigned long long*)p, v.u, __ATOMIC_RELAXED, __HIP_MEMORY_SCOPE_AGENT);
}

// Zero the polled word of each shard line. Stream-ordered before the main
// kernel; replay-proof (no dependence on the ws poison value).
__global__ __launch_bounds__(512) void init_rdy(unsigned* rdy) {
    int i = threadIdx.x;
    if (i < NLINES) rdy[(size_t)i * SHARD_STRIDE] = 0u;
}

// cpt/parents NOT __restrict__: publishes to `out` may alias, so the compiler
// cannot sink the CPT prefetch past the publish stores (R6-verified).
__global__ __launch_bounds__(TPB, 4) void bayes_flow7(
    const float* root_logits,   // [M]
    const float* cpt,           // [L, M, C]
    const int*   parents,       // [L, M, K]
    float*       out,           // [(L+1)*M]
    unsigned*    rdy)           // [(L+1)*NSHARD*SHARD_STRIDE]
{
    const int tid   = threadIdx.x;
    const int lane  = tid & 63;
    const int b     = blockIdx.x;
    const int gwave = b * WPB + (tid >> 6);
    const int mA    = gwave << 1;   // block owns contiguous nodes [b*32, b*32+32)
    const int mB    = mA | 1;
    const int c0    = lane << 2;
    const int shard = b >> 3;       // 8 blocks per shard, 32 shards

    // ---- prologue: root + parent-index + layer-0 CPT loads ----
    float rl = 0.0f;
    if (tid < NPB) rl = root_logits[b * NPB + tid];

    int pidx[N_LAYERS];
    if (lane < 2 * K_PAR) {
        const int node = (lane < K_PAR) ? mA : mB;
#pragma unroll
        for (int l = 0; l < N_LAYERS; ++l)
            pidx[l] = parents[((size_t)l * M_NODES + node) * K_PAR + (lane & 7)];
    }

    float4 qAc = *reinterpret_cast<const float4*>(cpt + (size_t)mA * C_CFG + c0);
    float4 qBc = *reinterpret_cast<const float4*>(cpt + (size_t)mB * C_CFG + c0);

    // publish roots (value>0 == ready); __syncthreads drains all waves' vmcnt,
    // then one counter add per block for layer-0's gate
    if (tid < NPB) astoref(out + b * NPB + tid, fsig(rl));
    __syncthreads();
    if (tid == 0)
        __hip_atomic_fetch_add(rdy + (size_t)shard * SHARD_STRIDE, 32u,
                               __ATOMIC_RELAXED, __HIP_MEMORY_SCOPE_AGENT);

    const float* prev = out;
    float*       cur  = out + M_NODES;

#pragma unroll
    for (int l = 0; l < N_LAYERS; ++l) {
        // (1) gate: wave 0 polls layer l's 32 shard counters. The vmem queue is
        // CLEAN here (previous prefetch drained by last iteration's rotate+pin),
        // so poll loads retire at L3 latency, not behind HBM streams.
        if (tid < 64) {
            const unsigned* base = rdy + (size_t)l * NSHARD * SHARD_STRIDE;
            int budget = 1 << 22;
            for (;;) {
                bool ok = true;
                if (lane < NSHARD) ok = (aloadu(base + (size_t)lane * SHARD_STRIDE) >= GATE_TARGET);
                if (__all(ok) || --budget <= 0) break;
                __builtin_amdgcn_s_sleep(1);
            }
        }
        __syncthreads();   // also a compiler memory fence: prefetch below cannot hoist above

        // (2) issue gather loads FIRST — oldest in queue, retires first (in-order)
        float pv = 1.0f;
        const float* ap = prev + ((lane < 2 * K_PAR) ? pidx[l] : 0);
        if (lane < 2 * K_PAR) pv = aloadf(ap);

        // (3) issue NEXT layer's CPT prefetch BEHIND the gather: vmcnt(2) frees
        // pv while the 8 MB/layer CPT stream overlaps compute+publish+next gate
        float4 qAn = {0, 0, 0, 0}, qBn = {0, 0, 0, 0};
        if (l + 1 < N_LAYERS) {
            qAn = *reinterpret_cast<const float4*>(cpt + ((size_t)(l + 1) * M_NODES + mA) * C_CFG + c0);
            qBn = *reinterpret_cast<const float4*>(cpt + ((size_t)(l + 1) * M_NODES + mB) * C_CFG + c0);
        }

        // (4) parent-independent VALU work fills the gather-latency window
        const float sA0 = fsig(qAc.x), sA1 = fsig(qAc.y), sA2 = fsig(qAc.z), sA3 = fsig(qAc.w);
        const float sB0 = fsig(qBc.x), sB1 = fsig(qBc.y), sB2 = fsig(qBc.z), sB3 = fsig(qBc.w);

        // (5) spin on the gathered values (normally ready on first check; the
        // value>0 re-check is the true correctness guard under relaxed order)
        if (lane < 2 * K_PAR) {
            int tries = 0;
            while (!(pv > 0.0f)) {
                if (++tries > 4) __builtin_amdgcn_s_sleep(2);
                pv = aloadf(ap);
            }
        }

        // (6) broadcast the 8 parent marginals of each node to all 64 lanes
        float pAv[K_PAR], pBv[K_PAR];
#pragma unroll
        for (int j = 0; j < K_PAR; ++j) {
            pAv[j] = __shfl(pv, j, 64);
            pBv[j] = __shfl(pv, K_PAR + j, 64);
        }

        // (7) config weights: top 6 bits fixed per lane, last 2 = lane's 4 configs
        float prefA = 1.0f, prefB = 1.0f;
#pragma unroll
        for (int j = 0; j < 6; ++j) {
            const int bit = (c0 >> (7 - j)) & 1;
            prefA *= bit ? pAv[j] : (1.0f - pAv[j]);
            prefB *= bit ? pBv[j] : (1.0f - pBv[j]);
        }
        const float p6A = pAv[6], p7A = pAv[7], q6A = 1.0f - p6A, q7A = 1.0f - p7A;
        const float p6B = pBv[6], p7B = pBv[7], q6B = 1.0f - p6B, q7B = 1.0f - p7B;

        float sA = sA0 * (prefA * q6A * q7A) + sA1 * (prefA * q6A * p7A)
                 + sA2 * (prefA * p6A * q7A) + sA3 * (prefA * p6A * p7A);
        float sB = sB0 * (prefB * q6B * q7B) + sB1 * (prefB * q6B * p7B)
                 + sB2 * (prefB * p6B * q7B) + sB3 * (prefB * p6B * p7B);

        // (8) 64-lane reductions; lane0 publishes both nodes in one 8B store
#pragma unroll
        for (int off = 32; off; off >>= 1) {
            sA += __shfl_xor(sA, off, 64);
            sB += __shfl_xor(sB, off, 64);
        }
        if (lane == 0) astore2(cur + mA, sA, sB);

        // (9) count this block's publishes for layer l+1's gate
        if (l + 1 < N_LAYERS) {
            __syncthreads();
            if (tid == 0)
                __hip_atomic_fetch_add(rdy + ((size_t)(l + 1) * NSHARD + shard) * SHARD_STRIDE,
                                       32u, __ATOMIC_RELAXED, __HIP_MEMORY_SCOPE_AGENT);
        }

        // (10) rotate + pin: forces the prefetch to materialize (drains vmcnt)
        // HERE — after publish/counter — so the next gate starts with a clean queue
        qAc = qAn; qBc = qBn;
        asm volatile("" : "+v"(qAc.x), "+v"(qAc.y), "+v"(qAc.z), "+v"(qAc.w),
                          "+v"(qBc.x), "+v"(qBc.y), "+v"(qBc.z), "+v"(qBc.w));

        prev = cur;
        cur += M_NODES;
    }
}

extern "C" void kernel_launch(void* const* d_in, const int* in_sizes, int n_in,
                              void* d_out, int out_size, void* d_ws, size_t ws_size,
                              hipStream_t stream) {
    const float* root_logits = (const float*)d_in[0];
    const float* cpt_logits  = (const float*)d_in[1];
    const int*   parents     = (const int*)d_in[2];
    float*       out         = (float*)d_out;
    unsigned*    rdy         = (unsigned*)d_ws;

    init_rdy<<<1, 512, 0, stream>>>(rdy);
    bayes_flow7<<<NBLOCKS, TPB, 0, stream>>>(root_logits, cpt_logits, parents, out, rdy);
}